// Round 7
// baseline (483.394 us; speedup 1.0000x reference)
//
#include <hip/hip_runtime.h>
#include <cstdint>

// DecoderAttentionRotary: B=2, L=2048, D=2048, H=16, HD=128, R=32
// R7: (1) attn: swapped QK^T (mfma(K,Q)) -> q lane-local; b64 P stores
// (4 instead of 16 b16, kills bank conflicts); 2-shfl softmax reduce;
// unpaired heavy-first grid (32,32) -> 4 blocks/CU.
// (2) QKV GEMMs fused into one N=6144 hgemm + single full-Wqkv transW.
// ws (92 MB): Qh|Kh|Vh|xh(=Oh) f16 + WT f16 (6144x2048).

namespace {

constexpr int B_ = 2, L_ = 2048, D_ = 2048, H_ = 16, HD_ = 128, R_ = 32;
constexpr float SCALE_ = 0.08838834764831845f;   // 128^-0.5

typedef _Float16 f16;
typedef __attribute__((ext_vector_type(8))) _Float16 f16x8;
typedef __attribute__((ext_vector_type(4))) _Float16 f16x4;
typedef __attribute__((ext_vector_type(8))) unsigned short u16x8;
typedef __attribute__((ext_vector_type(4))) float    f32x4;

__device__ __forceinline__ void gload_lds16(const void* g, void* l) {
    __builtin_amdgcn_global_load_lds(
        (const __attribute__((address_space(1))) void*)g,
        (__attribute__((address_space(3))) void*)l, 16, 0, 0);
}

// ---------------------------------------------------------------------------
// cast x f32 -> f16
// ---------------------------------------------------------------------------
__global__ __launch_bounds__(256) void cast_x_k(const float* __restrict__ x,
                                                f16* __restrict__ xh)
{
    const size_t i = ((size_t)blockIdx.x * 256 + threadIdx.x) * 4;
    const float4 v = *(const float4*)&x[i];
    f16x4 h; h[0] = (f16)v.x; h[1] = (f16)v.y; h[2] = (f16)v.z; h[3] = (f16)v.w;
    *(f16x4*)&xh[i] = h;
}

// ---------------------------------------------------------------------------
// Transpose-cast W[k][n] -> WT[n][k] f16. STRIDE = row stride of W (N total).
// 32x32 LDS tile, both phases coalesced.
// ---------------------------------------------------------------------------
template <int STRIDE>
__global__ __launch_bounds__(256) void transW_k(const float* __restrict__ W,
                                                f16* __restrict__ WT)
{
    const int t = threadIdx.x;
    const int n0 = blockIdx.x * 32, k0 = blockIdx.y * 32;

    __shared__ float tl[32][33];

    const int kr = t >> 3, cc = (t & 7) * 4;
    const float4 v = *(const float4*)&W[(size_t)(k0 + kr) * STRIDE + n0 + cc];
    tl[kr][cc + 0] = v.x; tl[kr][cc + 1] = v.y;
    tl[kr][cc + 2] = v.z; tl[kr][cc + 3] = v.w;
    __syncthreads();

    const int nr = t >> 3, kk = (t & 7) * 4;
    f16x4 w;
    w[0] = (f16)tl[kk + 0][nr]; w[1] = (f16)tl[kk + 1][nr];
    w[2] = (f16)tl[kk + 2][nr]; w[3] = (f16)tl[kk + 3][nr];
    *(f16x4*)&WT[(size_t)(n0 + nr) * 2048 + k0 + kk] = w;
}

// ---------------------------------------------------------------------------
// f16 MFMA GEMM (m97-structure, R5/R6-proven core).
// MODE 0: N=2048, float out + bias. MODE 1: N=6144 fused QKV, f16 scatter
// to Q/K/V (B,H,L,HD): head-block = n/384, r = n%384, sel = r>>7, d = r&127.
// ---------------------------------------------------------------------------
template <int MODE>
__global__ __launch_bounds__(256) void hgemm_k(
    const f16* __restrict__ A, const f16* __restrict__ Bt,
    const float* __restrict__ bias, float* __restrict__ Cf,
    f16* __restrict__ Qp, f16* __restrict__ Kp, f16* __restrict__ Vp)
{
    const int tid  = threadIdx.x;
    const int lane = tid & 63;
    const int wid  = tid >> 6;
    const int n0 = blockIdx.x * 128, m0 = blockIdx.y * 128;
    const int wm = (wid >> 1) * 64, wn = (wid & 1) * 64;

    __shared__ uint4 ldsb[1024];              // 16 KB: A 8 KB | B 8 KB
    char* AsB = (char*)ldsb;
    char* BsB = AsB + 8192;

    int gOffA[2], gOffB[2];
    char *ldsA[2], *ldsB[2];
    #pragma unroll
    for (int i = 0; i < 2; ++i) {
        const int j = 2 * wid + i;
        const int t = j * 64 + lane;
        const int m  = t >> 2;
        const int kc = (t & 3) ^ ((t >> 3) & 3);
        gOffA[i] = (m0 + m) * 2048 + kc * 8;
        gOffB[i] = (n0 + m) * 2048 + kc * 8;
        ldsA[i] = AsB + j * 1024;
        ldsB[i] = BsB + j * 1024;
    }

    const int rowa = wm + (lane & 15);
    const int rowb = wn + (lane & 15);
    const int aBase = rowa * 64 + (((lane >> 4) ^ ((rowa >> 1) & 3)) << 4);
    const int bBase = rowb * 64 + (((lane >> 4) ^ ((rowb >> 1) & 3)) << 4);

    f32x4 acc[4][4];
    #pragma unroll
    for (int i = 0; i < 4; ++i)
        #pragma unroll
        for (int j = 0; j < 4; ++j)
            acc[i][j] = (f32x4){0.f, 0.f, 0.f, 0.f};

    for (int k0 = 0; k0 < 2048; k0 += 32) {
        __syncthreads();
        #pragma unroll
        for (int i = 0; i < 2; ++i) {
            gload_lds16(A  + (size_t)gOffA[i] + k0, ldsA[i]);
            gload_lds16(Bt + (size_t)gOffB[i] + k0, ldsB[i]);
        }
        __syncthreads();

        f16x8 af[4], bf[4];
        #pragma unroll
        for (int mf = 0; mf < 4; ++mf) af[mf] = *(const f16x8*)(AsB + aBase + mf * 1024);
        #pragma unroll
        for (int nf = 0; nf < 4; ++nf) bf[nf] = *(const f16x8*)(BsB + bBase + nf * 1024);
        #pragma unroll
        for (int mf = 0; mf < 4; ++mf)
            #pragma unroll
            for (int nf = 0; nf < 4; ++nf)
                acc[mf][nf] = __builtin_amdgcn_mfma_f32_16x16x32_f16(
                    af[mf], bf[nf], acc[mf][nf], 0, 0, 0);
    }

    // D layout: col = lane&15, row = (lane>>4)*4 + r (m89-verified)
    #pragma unroll
    for (int nf = 0; nf < 4; ++nf) {
        const int col = n0 + wn + nf * 16 + (lane & 15);
        const float bn = bias[col];
        #pragma unroll
        for (int mf = 0; mf < 4; ++mf) {
            const int rbase = m0 + wm + mf * 16 + ((lane >> 4) << 2);
            #pragma unroll
            for (int r = 0; r < 4; ++r) {
                const float v = acc[mf][nf][r] + bn;
                const int m = rbase + r;
                if (MODE == 0) {
                    Cf[(size_t)m * 2048 + col] = v;
                } else {
                    const int b = m >> 11, l = m & (L_ - 1);
                    const int hseg = col / 384;
                    const int rr = col - hseg * 384;
                    const int sel = rr >> 7, d = rr & 127;
                    f16* dst = (sel == 0) ? Qp : (sel == 1) ? Kp : Vp;
                    dst[((size_t)(b * H_ + hseg) * L_ + l) * HD_ + d] = (f16)v;
                }
            }
        }
    }
}

// ---------------------------------------------------------------------------
// NeoX RoPE in place on f16 Q and K, first R_=32 dims.
// ---------------------------------------------------------------------------
__global__ __launch_bounds__(256) void rope_k(
    f16* __restrict__ Qp, f16* __restrict__ Kp,
    const float* __restrict__ cosp, const float* __restrict__ sinp)
{
    const int idx = blockIdx.x * 256 + threadIdx.x;
    const int j = idx & 15;
    const int bhl = idx >> 4;
    const int l = bhl & (L_ - 1);
    const float c = cosp[l * R_ + j];
    const float s = sinp[l * R_ + j];
    f16* qp = Qp + (size_t)bhl * HD_;
    f16* kp = Kp + (size_t)bhl * HD_;
    const float q1 = (float)qp[j], q2 = (float)qp[j + 16];
    qp[j]      = (f16)(q1 * c - q2 * s);
    qp[j + 16] = (f16)(q2 * c + q1 * s);
    const float k1 = (float)kp[j], k2 = (float)kp[j + 16];
    kp[j]      = (f16)(k1 * c - k2 * s);
    kp[j + 16] = (f16)(k2 * c + k1 * s);
}

// ---------------------------------------------------------------------------
// MFMA flash attention, swapped QK^T form.
// S^T = mfma(K_frag, Q_frag): lane holds q = lc (fixed), k = ks*16+lr*4+r
// (r-contiguous) -> softmax stats per-lane scalar (2 shfl reduce), P stored
// as 4 b64 per tile (was 16 b16). PV path identical to R6 (passing).
// Grid (32, 32) heavy-first (qe = 31 - bx); 40 KB LDS -> 4 blocks/CU.
// ---------------------------------------------------------------------------
__global__ __launch_bounds__(256) void attn3_k(
    const f16* __restrict__ Qh, const f16* __restrict__ Kh,
    const f16* __restrict__ Vh, f16* __restrict__ Oh)
{
    const int tid  = threadIdx.x;
    const int lane = tid & 63;
    const int wid  = tid >> 6;
    const int qe   = 31 - (int)blockIdx.x;   // heavy tiles first
    const int bh   = blockIdx.y;             // b*H + h
    const int lr   = lane >> 4;              // 0..3
    const int lc   = lane & 15;
    const int l7   = lane & 7;

    __shared__ f16 Ksh[64 * 128];
    __shared__ f16 Vts[128 * 64];
    __shared__ f16 Pls[4][16 * 64];

    const f16* Qb = Qh + (size_t)bh * (L_ * HD_);
    const f16* Kb = Kh + (size_t)bh * (L_ * HD_);
    const f16* Vb = Vh + (size_t)bh * (L_ * HD_);
    char* const KshB = (char*)Ksh;
    char* const VtsB = (char*)Vts;
    char* const PwB  = (char*)(&Pls[wid][0]);

    const int q0  = qe * 64;
    const int wq0 = q0 + wid * 16;

    // Q fragments: row = wq0 + lc, k = j*32 + lr*8 .. +8 (B-operand now)
    f16x8 qa[4];
    #pragma unroll
    for (int j = 0; j < 4; ++j)
        qa[j] = *(const f16x8*)&Qb[(size_t)(wq0 + lc) * HD_ + j * 32 + lr * 8];

    f32x4 of[8];
    #pragma unroll
    for (int ds = 0; ds < 8; ++ds) of[ds] = (f32x4){0.f, 0.f, 0.f, 0.f};
    float m_run = -1e30f, l_run = 0.f;       // stats for q-row (wq0 + lc)

    for (int t = 0; t <= qe; ++t) {
        const int k0 = t * 64;
        __syncthreads();
        // ---- stage K: linear LDS, pre-swizzled global source ----
        #pragma unroll
        for (int i = 0; i < 4; ++i) {
            const int slot = i * 256 + tid;
            const int row = slot >> 4, cch = slot & 15;
            const f16* src = Kb + (size_t)(k0 + row) * HD_ + (cch ^ (row & 7)) * 8;
            char* dst = KshB + (i * 256 + wid * 64) * 16;   // wave-uniform
            gload_lds16(src, dst);
        }
        // ---- stage V transposed: Vt[d][k], k-pair packed b32 ----
        #pragma unroll
        for (int rnd = 0; rnd < 2; ++rnd) {
            const int pc = rnd * 256 + tid;
            const int kp = pc & 31, dc = pc >> 5;
            const f16x8 va  = *(const f16x8*)&Vb[(size_t)(k0 + 2 * kp) * HD_ + dc * 8];
            const f16x8 vb2 = *(const f16x8*)&Vb[(size_t)(k0 + 2 * kp + 1) * HD_ + dc * 8];
            const u16x8 au = *(const u16x8*)&va;
            const u16x8 bu = *(const u16x8*)&vb2;
            #pragma unroll
            for (int i = 0; i < 8; ++i) {
                const int d = dc * 8 + i;
                const unsigned int pv = (unsigned)au[i] | ((unsigned)bu[i] << 16);
                *(unsigned int*)(VtsB + d * 128 + ((4 * kp) ^ ((d & 7) << 4))) = pv;
            }
        }
        __syncthreads();

        // ---- S^T = K Q^T (swapped): lane: q=lc, k=ks*16+lr*4+r ----
        f32x4 sacc[4];
        #pragma unroll
        for (int ks = 0; ks < 4; ++ks) sacc[ks] = (f32x4){0.f, 0.f, 0.f, 0.f};
        #pragma unroll
        for (int ks = 0; ks < 4; ++ks) {
            const int rowk = ks * 16 + lc;
            f16x8 kb[4];
            #pragma unroll
            for (int j = 0; j < 4; ++j)
                kb[j] = *(const f16x8*)(KshB + rowk * 256 + (((j * 4 + lr) ^ l7) * 16));
            #pragma unroll
            for (int j = 0; j < 4; ++j)
                sacc[ks] = __builtin_amdgcn_mfma_f32_16x16x32_f16(
                    kb[j], qa[j], sacc[ks], 0, 0, 0);
        }
        #pragma unroll
        for (int ks = 0; ks < 4; ++ks)
            #pragma unroll
            for (int r = 0; r < 4; ++r) sacc[ks][r] *= SCALE_;
        if (t == qe) {   // causal mask on diagonal tile
            #pragma unroll
            for (int ks = 0; ks < 4; ++ks)
                #pragma unroll
                for (int r = 0; r < 4; ++r)
                    if (k0 + ks * 16 + lr * 4 + r > wq0 + lc) sacc[ks][r] = -1e30f;
        }

        // ---- online softmax: lane-local 16-max + 2-shfl reduce ----
        float mx = sacc[0][0];
        #pragma unroll
        for (int ks = 0; ks < 4; ++ks)
            #pragma unroll
            for (int r = 0; r < 4; ++r) mx = fmaxf(mx, sacc[ks][r]);
        mx = fmaxf(mx, __shfl_xor(mx, 16));
        mx = fmaxf(mx, __shfl_xor(mx, 32));
        mx = fmaxf(mx, m_run);
        const float alpha = __expf(m_run - mx);
        m_run = mx;
        float ls = 0.f;
        #pragma unroll
        for (int ks = 0; ks < 4; ++ks)
            #pragma unroll
            for (int r = 0; r < 4; ++r) {
                const float p = __expf(sacc[ks][r] - mx);
                ls += p;
                sacc[ks][r] = p;
            }
        // P store: row q=lc, one b64 per ks (k-contiguous r)
        #pragma unroll
        for (int ks = 0; ks < 4; ++ks) {
            f16x4 h4;
            h4[0] = (f16)sacc[ks][0]; h4[1] = (f16)sacc[ks][1];
            h4[2] = (f16)sacc[ks][2]; h4[3] = (f16)sacc[ks][3];
            *(f16x4*)(PwB + lc * 128 + ((ks * 32 + lr * 8) ^ ((lc & 7) << 4))) = h4;
        }
        ls += __shfl_xor(ls, 16);
        ls += __shfl_xor(ls, 32);
        l_run = l_run * alpha + ls;
        // alpha for O rows q = wq0 + lr*4 + r lives in lane (lr*4+r)
        float af4[4];
        #pragma unroll
        for (int r = 0; r < 4; ++r) af4[r] = __shfl(alpha, lr * 4 + r);
        #pragma unroll
        for (int ds = 0; ds < 8; ++ds)
            #pragma unroll
            for (int r = 0; r < 4; ++r) of[ds][r] *= af4[r];

        // ---- O += P V (identical to R6) ----
        f16x8 pa[2];
        #pragma unroll
        for (int kc = 0; kc < 2; ++kc)
            pa[kc] = *(const f16x8*)(PwB + lc * 128 +
                     ((lr * 16 + kc * 64) ^ ((lc & 7) << 4)));
        #pragma unroll
        for (int ds = 0; ds < 8; ++ds) {
            const int d = ds * 16 + lc;
            #pragma unroll
            for (int kc = 0; kc < 2; ++kc) {
                const f16x8 vb = *(const f16x8*)(VtsB + d * 128 +
                                 ((lr * 16 + kc * 64) ^ ((d & 7) << 4)));
                of[ds] = __builtin_amdgcn_mfma_f32_16x16x32_f16(
                    pa[kc], vb, of[ds], 0, 0, 0);
            }
        }
    } // KV tiles

    // ---- epilogue ----
    const int b = bh >> 4, h = bh & (H_ - 1);
    float li[4];
    #pragma unroll
    for (int r = 0; r < 4; ++r) li[r] = __shfl(l_run, lr * 4 + r);
    #pragma unroll
    for (int r = 0; r < 4; ++r) {
        const int q = wq0 + lr * 4 + r;
        const float inv = 1.0f / li[r];
        f16* orow = Oh + ((size_t)(b * L_ + q)) * D_ + h * HD_;
        #pragma unroll
        for (int ds = 0; ds < 8; ++ds)
            orow[ds * 16 + lc] = (f16)(of[ds][r] * inv);
    }
}

} // anonymous namespace

extern "C" void kernel_launch(void* const* d_in, const int* in_sizes, int n_in,
                              void* d_out, int out_size, void* d_ws, size_t ws_size,
                              hipStream_t stream)
{
    (void)in_sizes; (void)n_in; (void)out_size; (void)ws_size;

    const float* x    = (const float*)d_in[0];
    const float* cosp = (const float*)d_in[1];
    const float* sinp = (const float*)d_in[2];
    const float* Wqkv = (const float*)d_in[3];
    const float* bqkv = (const float*)d_in[4];
    const float* Wd   = (const float*)d_in[5];
    const float* bd   = (const float*)d_in[6];
    float* out = (float*)d_out;

    const size_t SZ = (size_t)B_ * H_ * L_ * HD_;   // 8.39M elems
    f16* Qh = (f16*)d_ws;
    f16* Kh = Qh + SZ;
    f16* Vh = Kh + SZ;
    f16* xh = Vh + SZ;
    f16* Oh = xh;                     // alias: xh dead after QKV GEMM
    f16* WT = xh + SZ;                // 6144x2048 f16 = 25.2 MB (also Wd 8.4 MB)
    // peak ws: 4*16.78 + 25.2 = 92.3 MB

    cast_x_k<<<8192, 256, 0, stream>>>(x, xh);

    // fused QKV: transpose full Wqkv -> WT[6144][2048], one hgemm N=6144
    transW_k<6144><<<dim3(192, 64), 256, 0, stream>>>(Wqkv, WT);
    hgemm_k<1><<<dim3(48, 32), 256, 0, stream>>>(xh, WT, bqkv, nullptr, Qh, Kh, Vh);

    rope_k<<<4096, 256, 0, stream>>>(Qh, Kh, cosp, sinp);

    attn3_k<<<dim3(32, 32), 256, 0, stream>>>(Qh, Kh, Vh, Oh);

    transW_k<2048><<<dim3(64, 64), 256, 0, stream>>>(Wd, WT);
    hgemm_k<0><<<dim3(16, 32), 256, 0, stream>>>(Oh, WT, bd, out, nullptr, nullptr, nullptr);
}

// Round 8
// 476.024 us; speedup vs baseline: 1.0155x; 1.0155x over previous
//
#include <hip/hip_runtime.h>
#include <cstdint>

// DecoderAttentionRotary: B=2, L=2048, D=2048, H=16, HD=128, R=32
// R8: attn = R6's paired-balanced 2-phase structure (grid 16x32, 17 staged
// tiles/block, balanced) + R7's swapped QK^T softmax + BKV=128 (halves
// barriers and softmax passes). LDS 80KB. GEMM stack unchanged from R7
// (fused QKV N=6144, m97-structure hgemm).
// ws (92 MB): Qh|Kh|Vh|xh(=Oh) f16 + WT f16 (6144x2048).

namespace {

constexpr int B_ = 2, L_ = 2048, D_ = 2048, H_ = 16, HD_ = 128, R_ = 32;
constexpr float SCALE_ = 0.08838834764831845f;   // 128^-0.5

typedef _Float16 f16;
typedef __attribute__((ext_vector_type(8))) _Float16 f16x8;
typedef __attribute__((ext_vector_type(4))) _Float16 f16x4;
typedef __attribute__((ext_vector_type(8))) unsigned short u16x8;
typedef __attribute__((ext_vector_type(4))) float    f32x4;

__device__ __forceinline__ void gload_lds16(const void* g, void* l) {
    __builtin_amdgcn_global_load_lds(
        (const __attribute__((address_space(1))) void*)g,
        (__attribute__((address_space(3))) void*)l, 16, 0, 0);
}

// ---------------------------------------------------------------------------
// cast x f32 -> f16
// ---------------------------------------------------------------------------
__global__ __launch_bounds__(256) void cast_x_k(const float* __restrict__ x,
                                                f16* __restrict__ xh)
{
    const size_t i = ((size_t)blockIdx.x * 256 + threadIdx.x) * 4;
    const float4 v = *(const float4*)&x[i];
    f16x4 h; h[0] = (f16)v.x; h[1] = (f16)v.y; h[2] = (f16)v.z; h[3] = (f16)v.w;
    *(f16x4*)&xh[i] = h;
}

// ---------------------------------------------------------------------------
// Transpose-cast W[k][n] -> WT[n][k] f16. STRIDE = row stride of W.
// ---------------------------------------------------------------------------
template <int STRIDE>
__global__ __launch_bounds__(256) void transW_k(const float* __restrict__ W,
                                                f16* __restrict__ WT)
{
    const int t = threadIdx.x;
    const int n0 = blockIdx.x * 32, k0 = blockIdx.y * 32;

    __shared__ float tl[32][33];

    const int kr = t >> 3, cc = (t & 7) * 4;
    const float4 v = *(const float4*)&W[(size_t)(k0 + kr) * STRIDE + n0 + cc];
    tl[kr][cc + 0] = v.x; tl[kr][cc + 1] = v.y;
    tl[kr][cc + 2] = v.z; tl[kr][cc + 3] = v.w;
    __syncthreads();

    const int nr = t >> 3, kk = (t & 7) * 4;
    f16x4 w;
    w[0] = (f16)tl[kk + 0][nr]; w[1] = (f16)tl[kk + 1][nr];
    w[2] = (f16)tl[kk + 2][nr]; w[3] = (f16)tl[kk + 3][nr];
    *(f16x4*)&WT[(size_t)(n0 + nr) * 2048 + k0 + kk] = w;
}

// ---------------------------------------------------------------------------
// f16 MFMA GEMM (m97-structure, R5-R7 proven).
// MODE 0: N=2048, float out + bias. MODE 1: N=6144 fused QKV f16 scatter.
// ---------------------------------------------------------------------------
template <int MODE>
__global__ __launch_bounds__(256) void hgemm_k(
    const f16* __restrict__ A, const f16* __restrict__ Bt,
    const float* __restrict__ bias, float* __restrict__ Cf,
    f16* __restrict__ Qp, f16* __restrict__ Kp, f16* __restrict__ Vp)
{
    const int tid  = threadIdx.x;
    const int lane = tid & 63;
    const int wid  = tid >> 6;
    const int n0 = blockIdx.x * 128, m0 = blockIdx.y * 128;
    const int wm = (wid >> 1) * 64, wn = (wid & 1) * 64;

    __shared__ uint4 ldsb[1024];              // 16 KB: A 8 KB | B 8 KB
    char* AsB = (char*)ldsb;
    char* BsB = AsB + 8192;

    int gOffA[2], gOffB[2];
    char *ldsA[2], *ldsB[2];
    #pragma unroll
    for (int i = 0; i < 2; ++i) {
        const int j = 2 * wid + i;
        const int t = j * 64 + lane;
        const int m  = t >> 2;
        const int kc = (t & 3) ^ ((t >> 3) & 3);
        gOffA[i] = (m0 + m) * 2048 + kc * 8;
        gOffB[i] = (n0 + m) * 2048 + kc * 8;
        ldsA[i] = AsB + j * 1024;
        ldsB[i] = BsB + j * 1024;
    }

    const int rowa = wm + (lane & 15);
    const int rowb = wn + (lane & 15);
    const int aBase = rowa * 64 + (((lane >> 4) ^ ((rowa >> 1) & 3)) << 4);
    const int bBase = rowb * 64 + (((lane >> 4) ^ ((rowb >> 1) & 3)) << 4);

    f32x4 acc[4][4];
    #pragma unroll
    for (int i = 0; i < 4; ++i)
        #pragma unroll
        for (int j = 0; j < 4; ++j)
            acc[i][j] = (f32x4){0.f, 0.f, 0.f, 0.f};

    for (int k0 = 0; k0 < 2048; k0 += 32) {
        __syncthreads();
        #pragma unroll
        for (int i = 0; i < 2; ++i) {
            gload_lds16(A  + (size_t)gOffA[i] + k0, ldsA[i]);
            gload_lds16(Bt + (size_t)gOffB[i] + k0, ldsB[i]);
        }
        __syncthreads();

        f16x8 af[4], bf[4];
        #pragma unroll
        for (int mf = 0; mf < 4; ++mf) af[mf] = *(const f16x8*)(AsB + aBase + mf * 1024);
        #pragma unroll
        for (int nf = 0; nf < 4; ++nf) bf[nf] = *(const f16x8*)(BsB + bBase + nf * 1024);
        #pragma unroll
        for (int mf = 0; mf < 4; ++mf)
            #pragma unroll
            for (int nf = 0; nf < 4; ++nf)
                acc[mf][nf] = __builtin_amdgcn_mfma_f32_16x16x32_f16(
                    af[mf], bf[nf], acc[mf][nf], 0, 0, 0);
    }

    #pragma unroll
    for (int nf = 0; nf < 4; ++nf) {
        const int col = n0 + wn + nf * 16 + (lane & 15);
        const float bn = bias[col];
        #pragma unroll
        for (int mf = 0; mf < 4; ++mf) {
            const int rbase = m0 + wm + mf * 16 + ((lane >> 4) << 2);
            #pragma unroll
            for (int r = 0; r < 4; ++r) {
                const float v = acc[mf][nf][r] + bn;
                const int m = rbase + r;
                if (MODE == 0) {
                    Cf[(size_t)m * 2048 + col] = v;
                } else {
                    const int b = m >> 11, l = m & (L_ - 1);
                    const int hseg = col / 384;
                    const int rr = col - hseg * 384;
                    const int sel = rr >> 7, d = rr & 127;
                    f16* dst = (sel == 0) ? Qp : (sel == 1) ? Kp : Vp;
                    dst[((size_t)(b * H_ + hseg) * L_ + l) * HD_ + d] = (f16)v;
                }
            }
        }
    }
}

// ---------------------------------------------------------------------------
// NeoX RoPE in place on f16 Q and K, first R_=32 dims.
// ---------------------------------------------------------------------------
__global__ __launch_bounds__(256) void rope_k(
    f16* __restrict__ Qp, f16* __restrict__ Kp,
    const float* __restrict__ cosp, const float* __restrict__ sinp)
{
    const int idx = blockIdx.x * 256 + threadIdx.x;
    const int j = idx & 15;
    const int bhl = idx >> 4;
    const int l = bhl & (L_ - 1);
    const float c = cosp[l * R_ + j];
    const float s = sinp[l * R_ + j];
    f16* qp = Qp + (size_t)bhl * HD_;
    f16* kp = Kp + (size_t)bhl * HD_;
    const float q1 = (float)qp[j], q2 = (float)qp[j + 16];
    qp[j]      = (f16)(q1 * c - q2 * s);
    qp[j + 16] = (f16)(q2 * c + q1 * s);
    const float k1 = (float)kp[j], k2 = (float)kp[j + 16];
    kp[j]      = (f16)(k1 * c - k2 * s);
    kp[j + 16] = (f16)(k2 * c + k1 * s);
}

// ---------------------------------------------------------------------------
// MFMA flash attention: paired-balanced 2-phase (qt, 31-qt), BKV=128,
// swapped QK^T (lane q = lc; k = ks*16+lr*4+r lane-local). Per block:
// 17 staged 128-wide KV tiles (balanced for all qt; only last tile masked).
// LDS 80KB: Ksh[128][128] (swizzled gload_lds), Vt[128][256B] (reg-transpose,
// chunk^=(d&7)), P[4][16][256B] (b64 stores, chunk^=(lc&7)). Grid (16,32).
// ---------------------------------------------------------------------------
__global__ __launch_bounds__(256) void attn4_k(
    const f16* __restrict__ Qh, const f16* __restrict__ Kh,
    const f16* __restrict__ Vh, f16* __restrict__ Oh)
{
    const int tid  = threadIdx.x;
    const int lane = tid & 63;
    const int wid  = tid >> 6;
    const int qtb  = blockIdx.x;    // 0..15
    const int bh   = blockIdx.y;    // b*H + h
    const int lr   = lane >> 4;     // 0..3
    const int lc   = lane & 15;
    const int l7   = lane & 7;      // == lc & 7

    __shared__ f16 Ksh[128 * 128];          // 32 KB
    __shared__ f16 Vts[128 * 128];          // 32 KB (row = d, 256 B)
    __shared__ f16 Pls[4][16 * 128];        // 16 KB

    const f16* Qb = Qh + (size_t)bh * (L_ * HD_);
    const f16* Kb = Kh + (size_t)bh * (L_ * HD_);
    const f16* Vb = Vh + (size_t)bh * (L_ * HD_);
    char* const KshB = (char*)Ksh;
    char* const VtsB = (char*)Vts;
    char* const PwB  = (char*)(&Pls[wid][0]);

    #pragma unroll
    for (int ph = 0; ph < 2; ++ph) {
        const int qe  = ph ? (31 - qtb) : qtb;
        const int wq0 = qe * 64 + wid * 16;

        // Q fragments (B-operand of swapped QK^T): row wq0+lc, d = (j*4+lr)*8
        f16x8 qa[4];
        #pragma unroll
        for (int j = 0; j < 4; ++j)
            qa[j] = *(const f16x8*)&Qb[(size_t)(wq0 + lc) * HD_ + j * 32 + lr * 8];

        f32x4 of[8];
        #pragma unroll
        for (int ds = 0; ds < 8; ++ds) of[ds] = (f32x4){0.f, 0.f, 0.f, 0.f};
        float m_run = -1e30f, l_run = 0.f;   // stats for q-row (wq0 + lc)

        const int ntile = (qe + 2) >> 1;     // 128-wide KV tiles
        for (int t = 0; t < ntile; ++t) {
            const int k0 = t * 128;
            __syncthreads();
            // ---- stage K[128][128]: linear LDS, pre-swizzled source ----
            #pragma unroll
            for (int i = 0; i < 8; ++i) {
                const int slot = i * 256 + tid;
                const int row = slot >> 4, cch = slot & 15;
                const f16* src = Kb + (size_t)(k0 + row) * HD_ + (cch ^ (row & 7)) * 8;
                char* dst = KshB + (i * 256 + wid * 64) * 16;   // wave-uniform
                gload_lds16(src, dst);
            }
            // ---- stage V transposed: Vt[d][k 0..127], k-pair b32 writes ----
            #pragma unroll
            for (int rnd = 0; rnd < 4; ++rnd) {
                const int pc = rnd * 256 + tid;
                const int kp = pc & 63, dc = pc >> 6;
                const f16x8 va  = *(const f16x8*)&Vb[(size_t)(k0 + 2 * kp) * HD_ + dc * 8];
                const f16x8 vb2 = *(const f16x8*)&Vb[(size_t)(k0 + 2 * kp + 1) * HD_ + dc * 8];
                const u16x8 au = *(const u16x8*)&va;
                const u16x8 bu = *(const u16x8*)&vb2;
                #pragma unroll
                for (int i = 0; i < 8; ++i) {
                    const int d = dc * 8 + i;
                    const unsigned int pv = (unsigned)au[i] | ((unsigned)bu[i] << 16);
                    *(unsigned int*)(VtsB + d * 256 + ((4 * kp) ^ ((d & 7) << 4))) = pv;
                }
            }
            __syncthreads();

            // ---- S^T = K Q^T: lane q=lc, k = ks*16 + lr*4 + r ----
            f32x4 sacc[8];
            #pragma unroll
            for (int ks = 0; ks < 8; ++ks) sacc[ks] = (f32x4){0.f, 0.f, 0.f, 0.f};
            #pragma unroll
            for (int ks = 0; ks < 8; ++ks) {
                const int rowk = ks * 16 + lc;
                f16x8 kb[4];
                #pragma unroll
                for (int j = 0; j < 4; ++j)
                    kb[j] = *(const f16x8*)(KshB + rowk * 256 + (((j * 4 + lr) ^ l7) * 16));
                #pragma unroll
                for (int j = 0; j < 4; ++j)
                    sacc[ks] = __builtin_amdgcn_mfma_f32_16x16x32_f16(
                        kb[j], qa[j], sacc[ks], 0, 0, 0);
            }
            #pragma unroll
            for (int ks = 0; ks < 8; ++ks)
                #pragma unroll
                for (int r = 0; r < 4; ++r) sacc[ks][r] *= SCALE_;
            if (t == ntile - 1) {   // only the last tile can cross the diagonal
                #pragma unroll
                for (int ks = 0; ks < 8; ++ks)
                    #pragma unroll
                    for (int r = 0; r < 4; ++r)
                        if (k0 + ks * 16 + lr * 4 + r > wq0 + lc) sacc[ks][r] = -1e30f;
            }

            // ---- online softmax: 31 lane-local max + 2 shfl ----
            float mx = sacc[0][0];
            #pragma unroll
            for (int ks = 0; ks < 8; ++ks)
                #pragma unroll
                for (int r = 0; r < 4; ++r) mx = fmaxf(mx, sacc[ks][r]);
            mx = fmaxf(mx, __shfl_xor(mx, 16));
            mx = fmaxf(mx, __shfl_xor(mx, 32));
            mx = fmaxf(mx, m_run);
            const float alpha = __expf(m_run - mx);
            m_run = mx;
            float ls = 0.f;
            #pragma unroll
            for (int ks = 0; ks < 8; ++ks)
                #pragma unroll
                for (int r = 0; r < 4; ++r) {
                    const float p = __expf(sacc[ks][r] - mx);
                    ls += p;
                    sacc[ks][r] = p;
                }
            // P store: row q=lc (256B), one b64 per ks
            #pragma unroll
            for (int ks = 0; ks < 8; ++ks) {
                f16x4 h4;
                h4[0] = (f16)sacc[ks][0]; h4[1] = (f16)sacc[ks][1];
                h4[2] = (f16)sacc[ks][2]; h4[3] = (f16)sacc[ks][3];
                *(f16x4*)(PwB + lc * 256 + ((ks * 32 + lr * 8) ^ (l7 << 4))) = h4;
            }
            ls += __shfl_xor(ls, 16);
            ls += __shfl_xor(ls, 32);
            l_run = l_run * alpha + ls;
            // alpha for O rows q = wq0 + lr*4 + r lives in lane (lr*4+r)
            float af4[4];
            #pragma unroll
            for (int r = 0; r < 4; ++r) af4[r] = __shfl(alpha, lr * 4 + r);
            #pragma unroll
            for (int ds = 0; ds < 8; ++ds)
                #pragma unroll
                for (int r = 0; r < 4; ++r) of[ds][r] *= af4[r];

            // ---- O += P V: 4 k-blocks of 32 ----
            f16x8 pa[4];
            #pragma unroll
            for (int kc = 0; kc < 4; ++kc)
                pa[kc] = *(const f16x8*)(PwB + lc * 256 +
                         ((lr * 16 + kc * 64) ^ (l7 << 4)));
            #pragma unroll
            for (int ds = 0; ds < 8; ++ds) {
                const int d = ds * 16 + lc;
                #pragma unroll
                for (int kc = 0; kc < 4; ++kc) {
                    const f16x8 vb = *(const f16x8*)(VtsB + d * 256 +
                                     ((lr * 16 + kc * 64) ^ ((d & 7) << 4)));
                    of[ds] = __builtin_amdgcn_mfma_f32_16x16x32_f16(
                        pa[kc], vb, of[ds], 0, 0, 0);
                }
            }
        } // KV tiles

        // ---- epilogue ----
        const int b = bh >> 4, h = bh & (H_ - 1);
        float li[4];
        #pragma unroll
        for (int r = 0; r < 4; ++r) li[r] = __shfl(l_run, lr * 4 + r);
        #pragma unroll
        for (int r = 0; r < 4; ++r) {
            const int q = wq0 + lr * 4 + r;
            const float inv = 1.0f / li[r];
            f16* orow = Oh + ((size_t)(b * L_ + q)) * D_ + h * HD_;
            #pragma unroll
            for (int ds = 0; ds < 8; ++ds)
                orow[ds * 16 + lc] = (f16)(of[ds][r] * inv);
        }
    } // phases
}

} // anonymous namespace

extern "C" void kernel_launch(void* const* d_in, const int* in_sizes, int n_in,
                              void* d_out, int out_size, void* d_ws, size_t ws_size,
                              hipStream_t stream)
{
    (void)in_sizes; (void)n_in; (void)out_size; (void)ws_size;

    const float* x    = (const float*)d_in[0];
    const float* cosp = (const float*)d_in[1];
    const float* sinp = (const float*)d_in[2];
    const float* Wqkv = (const float*)d_in[3];
    const float* bqkv = (const float*)d_in[4];
    const float* Wd   = (const float*)d_in[5];
    const float* bd   = (const float*)d_in[6];
    float* out = (float*)d_out;

    const size_t SZ = (size_t)B_ * H_ * L_ * HD_;   // 8.39M elems
    f16* Qh = (f16*)d_ws;
    f16* Kh = Qh + SZ;
    f16* Vh = Kh + SZ;
    f16* xh = Vh + SZ;
    f16* Oh = xh;                     // alias: xh dead after QKV GEMM
    f16* WT = xh + SZ;                // 6144x2048 f16 = 25.2 MB
    // peak ws: 4*16.78 + 25.2 = 92.3 MB

    cast_x_k<<<8192, 256, 0, stream>>>(x, xh);

    transW_k<6144><<<dim3(192, 64), 256, 0, stream>>>(Wqkv, WT);
    hgemm_k<1><<<dim3(48, 32), 256, 0, stream>>>(xh, WT, bqkv, nullptr, Qh, Kh, Vh);

    rope_k<<<4096, 256, 0, stream>>>(Qh, Kh, cosp, sinp);

    attn4_k<<<dim3(16, 32), 256, 0, stream>>>(Qh, Kh, Vh, Oh);

    transW_k<2048><<<dim3(64, 64), 256, 0, stream>>>(Wd, WT);
    hgemm_k<0><<<dim3(16, 32), 256, 0, stream>>>(Oh, WT, bd, out, nullptr, nullptr, nullptr);
}